// Round 2
// baseline (243.778 us; speedup 1.0000x reference)
//
#include <hip/hip_runtime.h>

typedef unsigned short u16;
typedef __attribute__((ext_vector_type(8))) short bf16x8;
typedef __attribute__((ext_vector_type(4))) float f32x4;

#define LSTR 520  // bf16 elems per LDS row: 512 + 8 pad

// ---------------- workspace layout (bytes) ----------------
#define WS_STATE   0
#define WS_A0V     524288
#define WS_A0O     1048576
#define WS_QW      1572864
#define WS_QKV     2097152
#define WS_QUE     2621440
#define WS_A1V     3145728
#define WS_A1O     3670016
#define WS_VAL     4194304
#define WS_POL     4718592
#define WS_PEMB    4728832
#define WS_ROT     4737024
#define WS_KW      6834176
#define WS_VW      7358464
#define WS_PWR     7882752
#define WS_KK      7915520
#define WS_VV      7981056
#define WS_MEM     8046592
#define WS_ROTB    8570880
#define WS_A0VB    8574976
#define WS_A0OB    (WS_A0VB + 1024)
#define WS_QB      (WS_A0VB + 2048)
#define WS_KB      (WS_A0VB + 3072)
#define WS_VB      (WS_A0VB + 4096)
#define WS_QKVB    (WS_A0VB + 5120)
#define WS_QUEB    (WS_A0VB + 6144)
#define WS_A1VB    (WS_A0VB + 7168)
#define WS_A1OB    (WS_A0VB + 8192)
#define WS_VALB    (WS_A0VB + 9216)
#define WS_ANG     (WS_A0VB + 10240)
#define WS_ANB     (WS_A0VB + 11264)
#define WS_FNG     (WS_A0VB + 12288)
#define WS_FNB     (WS_A0VB + 13312)
#define WS_POLB    (WS_A0VB + 14336)

__device__ __forceinline__ float bf2f(u16 u) {
  union { unsigned int i; float f; } v; v.i = ((unsigned int)u) << 16; return v.f;
}
__device__ __forceinline__ u16 f2bf(float f) {
  union { float f; unsigned int i; } v; v.f = f;
  unsigned int r = v.i + 0x7fffu + ((v.i >> 16) & 1u);
  return (u16)(r >> 16);
}
__device__ __forceinline__ f32x4 MFMA(bf16x8 a, bf16x8 b, f32x4 c) {
  return __builtin_amdgcn_mfma_f32_16x16x32_bf16(a, b, c, 0, 0, 0);
}

// ---------------- dtype-canonicalizing staging ----------------
struct Job { const void* base; int eoff; int n; int dstoff; };
struct Jobs { Job j[31]; };

__global__ __launch_bounds__(256) void k_convert(Jobs jobs, const u16* __restrict__ probe,
                                                 char* __restrict__ ws) {
  // dtype probe: bf16 N(0,1) data -> exponent fields cluster in [114,140];
  // f32 data read as u16 -> even halves are ~uniform bits -> many outliers.
  int big = 0;
  for (int i = 0; i < 128; i += 2) {
    const int e = (probe[i] >> 7) & 0xFF;
    if (e > 140 || (e != 0 && e < 114)) ++big;
  }
  const bool f32in = big > 8;

  const Job jb = jobs.j[blockIdx.y];
  const int i0 = (blockIdx.x * 256 + threadIdx.x) * 8;
  if (i0 >= jb.n) return;
  u16* dst = (u16*)(ws + jb.dstoff);
  if (f32in) {
    const float* src = (const float*)jb.base + jb.eoff;
    if (i0 + 8 <= jb.n) {
      const float4 a = *(const float4*)(src + i0);
      const float4 b = *(const float4*)(src + i0 + 4);
      u16 o[8] = {f2bf(a.x), f2bf(a.y), f2bf(a.z), f2bf(a.w),
                  f2bf(b.x), f2bf(b.y), f2bf(b.z), f2bf(b.w)};
      *(uint4*)(dst + i0) = *(uint4*)o;
    } else {
      for (int k = i0; k < jb.n; ++k) dst[k] = f2bf(src[k]);
    }
  } else {
    const u16* src = (const u16*)jb.base + jb.eoff;
    if (i0 + 8 <= jb.n) {
      *(uint4*)(dst + i0) = *(const uint4*)(src + i0);
    } else {
      for (int k = i0; k < jb.n; ++k) dst[k] = src[k];
    }
  }
}

// ---- per-wave GEMM tile: Y[16x512] = A(LDS bf16 [16][LSTR]) @ W^T + bias
// MFMA 16x16x32 layouts: A: row=lane&15, k=(lane>>4)*8+j ; B: col=lane&15, k=(lane>>4)*8+j ;
// D: col=lane&15, row=(lane>>4)*4+reg.
__device__ __forceinline__ void gemm16(const u16* A, const u16* W, const u16* bias,
                                       int wid, int lane, f32x4 acc[8]) {
  const int rc = lane & 15;
  const int kb = lane >> 4;
  const bf16x8* ab = reinterpret_cast<const bf16x8*>(A) + rc * (LSTR / 8) + kb;
  const bf16x8* wb = reinterpret_cast<const bf16x8*>(W) + (wid * 128 + rc) * 64 + kb;
#pragma unroll
  for (int nt = 0; nt < 8; ++nt) acc[nt] = (f32x4){0.f, 0.f, 0.f, 0.f};
#pragma unroll
  for (int ks = 0; ks < 16; ++ks) {
    bf16x8 a = ab[ks * 4];
#pragma unroll
    for (int nt = 0; nt < 8; ++nt) acc[nt] = MFMA(a, wb[nt * 1024 + ks * 4], acc[nt]);
  }
#pragma unroll
  for (int nt = 0; nt < 8; ++nt) {
    const float bv = bf2f(bias[wid * 128 + nt * 16 + rc]);
#pragma unroll
    for (int r = 0; r < 4; ++r) acc[nt][r] += bv;
  }
}

__device__ __forceinline__ void store_bf(u16* dst, int wid, int lane, const f32x4 acc[8]) {
  const int cr = lane & 15, rb = (lane >> 4) * 4;
#pragma unroll
  for (int nt = 0; nt < 8; ++nt) {
    const int col = wid * 128 + nt * 16 + cr;
#pragma unroll
    for (int r = 0; r < 4; ++r) dst[(rb + r) * LSTR + col] = f2bf(acc[nt][r]);
  }
}

__device__ __forceinline__ void add_lds_bf(const u16* src, int wid, int lane, f32x4 acc[8]) {
  const int cr = lane & 15, rb = (lane >> 4) * 4;
#pragma unroll
  for (int nt = 0; nt < 8; ++nt) {
    const int col = wid * 128 + nt * 16 + cr;
#pragma unroll
    for (int r = 0; r < 4; ++r) acc[nt][r] += bf2f(src[(rb + r) * LSTR + col]);
  }
}

__device__ __forceinline__ void add_glb_bf(const u16* g, int wid, int lane, f32x4 acc[8]) {
  const int cr = lane & 15, rb = (lane >> 4) * 4;
#pragma unroll
  for (int nt = 0; nt < 8; ++nt) {
    const int col = wid * 128 + nt * 16 + cr;
#pragma unroll
    for (int r = 0; r < 4; ++r) acc[nt][r] += bf2f(g[(size_t)(rb + r) * 512 + col]);
  }
}

__device__ __forceinline__ void layer_norm_bf(const u16* X, u16* dst, const u16* g,
                                              const u16* b, int tid) {
  const int row = tid >> 4, c0 = tid & 15;
  float s = 0.f, q = 0.f;
  for (int c = c0; c < 512; c += 16) {
    const float v = bf2f(X[row * LSTR + c]);
    s += v; q += v * v;
  }
#pragma unroll
  for (int m = 1; m < 16; m <<= 1) {
    s += __shfl_xor(s, m, 64);
    q += __shfl_xor(q, m, 64);
  }
  const float mu = s * (1.f / 512.f);
  const float rs = rsqrtf(q * (1.f / 512.f) - mu * mu + 1e-5f);
  for (int c = c0; c < 512; c += 16) {
    const float v = (bf2f(X[row * LSTR + c]) - mu) * rs * bf2f(g[c]) + bf2f(b[c]);
    dst[row * LSTR + c] = f2bf(v);
  }
}

// ---- kernel 1: pwr[p][j][c] for 8 pieces: (8x512) @ rot_w(2048x512)^T + rot_b
__global__ __launch_bounds__(256) void k_pieces_rot(const u16* __restrict__ piece_emb,
                                                    const u16* __restrict__ rot_w,
                                                    const u16* __restrict__ rot_b,
                                                    u16* __restrict__ pwr_ws) {
  __shared__ __align__(16) u16 A[16 * LSTR];
  const int tid = threadIdx.x, lane = tid & 63, wid = tid >> 6;
  for (int idx = tid; idx < 16 * 64; idx += 256) {
    const int r = idx >> 6, c = idx & 63;
    uint4 v;
    if (r < 8) v = ((const uint4*)piece_emb)[r * 64 + c];
    else { v.x = v.y = v.z = v.w = 0u; }
    *(uint4*)&A[r * LSTR + c * 8] = v;
  }
  __syncthreads();
  const int rc = lane & 15, kb = lane >> 4;
  const int colbase = blockIdx.x * 128 + wid * 32;
  const bf16x8* ab = reinterpret_cast<const bf16x8*>(A) + rc * (LSTR / 8) + kb;
  const bf16x8* wb = reinterpret_cast<const bf16x8*>(rot_w) + (colbase + rc) * 64 + kb;
  f32x4 acc0 = (f32x4){0.f, 0.f, 0.f, 0.f}, acc1 = acc0;
#pragma unroll
  for (int ks = 0; ks < 16; ++ks) {
    bf16x8 a = ab[ks * 4];
    acc0 = MFMA(a, wb[ks * 4], acc0);
    acc1 = MFMA(a, wb[1024 + ks * 4], acc1);
  }
  const int cr = lane & 15, rb = (lane >> 4) * 4;
#pragma unroll
  for (int nt = 0; nt < 2; ++nt) {
    const int o = colbase + nt * 16 + cr;  // 0..2047 ; j = o>>9, c = o&511
    const float bv = bf2f(rot_b[o]);
#pragma unroll
    for (int r = 0; r < 4; ++r) {
      const int p = rb + r;
      const float val = (nt == 0 ? acc0[r] : acc1[r]) + bv;
      if (p < 8) pwr_ws[(size_t)(p * 4 + (o >> 9)) * 512 + (o & 511)] = f2bf(val);
    }
  }
}

// ---- kernel 2: kk/vv[p*4+j][c] = pwr @ {k_w,v_w}^T + bias (32x512), f32 out
__global__ __launch_bounds__(256) void k_pieces_kv(const u16* __restrict__ pwr_ws,
                                                   const u16* __restrict__ k_w,
                                                   const u16* __restrict__ k_b,
                                                   const u16* __restrict__ v_w,
                                                   const u16* __restrict__ v_b,
                                                   float* __restrict__ kk_ws,
                                                   float* __restrict__ vv_ws) {
  __shared__ __align__(16) u16 A[32 * LSTR];
  const int tid = threadIdx.x, lane = tid & 63, wid = tid >> 6;
  for (int idx = tid; idx < 32 * 64; idx += 256) {
    const int r = idx >> 6, c = idx & 63;
    *(uint4*)&A[r * LSTR + c * 8] = ((const uint4*)pwr_ws)[r * 64 + c];
  }
  __syncthreads();
  const int rc = lane & 15, kb = lane >> 4;
  const int col = blockIdx.x * 64 + wid * 16 + rc;
  const bf16x8* ab0 = reinterpret_cast<const bf16x8*>(A) + rc * (LSTR / 8) + kb;
  const bf16x8* ab1 = reinterpret_cast<const bf16x8*>(A) + (rc + 16) * (LSTR / 8) + kb;
  const bf16x8* wk = reinterpret_cast<const bf16x8*>(k_w) + col * 64 + kb;
  const bf16x8* wv = reinterpret_cast<const bf16x8*>(v_w) + col * 64 + kb;
  f32x4 ak0 = (f32x4){0.f, 0.f, 0.f, 0.f}, ak1 = ak0, av0 = ak0, av1 = ak0;
#pragma unroll
  for (int ks = 0; ks < 16; ++ks) {
    bf16x8 a0 = ab0[ks * 4], a1 = ab1[ks * 4];
    bf16x8 bk = wk[ks * 4], bv = wv[ks * 4];
    ak0 = MFMA(a0, bk, ak0);
    ak1 = MFMA(a1, bk, ak1);
    av0 = MFMA(a0, bv, av0);
    av1 = MFMA(a1, bv, av1);
  }
  const int rb = (lane >> 4) * 4;
  const float kbv = bf2f(k_b[col]), vbv = bf2f(v_b[col]);
#pragma unroll
  for (int r = 0; r < 4; ++r) {
    kk_ws[(size_t)(rb + r) * 512 + col] = ak0[r] + kbv;
    vv_ws[(size_t)(rb + r) * 512 + col] = av0[r] + vbv;
    kk_ws[(size_t)(rb + r + 16) * 512 + col] = ak1[r] + kbv;
    vv_ws[(size_t)(rb + r + 16) * 512 + col] = av1[r] + vbv;
  }
}

// ---- kernel 3: fused per-batch chain. 1 block = 16 batch rows.
__global__ __launch_bounds__(256) void k_main(
    const u16* __restrict__ state16, const u16* __restrict__ mem16,
    const int* __restrict__ queue, const char* __restrict__ ws,
    const float* __restrict__ kk_ws, const float* __restrict__ vv_ws,
    float* __restrict__ out_pol, float* __restrict__ out_val) {
  __shared__ __align__(16) u16 X[16 * LSTR];
  __shared__ __align__(16) u16 Y[16 * LSTR];
  __shared__ __align__(16) u16 Z[16 * LSTR];
  __shared__ int piece_s[16];
  __shared__ int qs_s;
  const int tid = threadIdx.x;
  const int lane = tid & 63, wid = tid >> 6;
  const int r0 = blockIdx.x * 16;

  const u16* a0v_w = (const u16*)(ws + WS_A0V);  const u16* a0v_b = (const u16*)(ws + WS_A0VB);
  const u16* a0o_w = (const u16*)(ws + WS_A0O);  const u16* a0o_b = (const u16*)(ws + WS_A0OB);
  const u16* q_w   = (const u16*)(ws + WS_QW);   const u16* q_b   = (const u16*)(ws + WS_QB);
  const u16* qkv_w = (const u16*)(ws + WS_QKV);  const u16* qkv_b = (const u16*)(ws + WS_QKVB);
  const u16* que_w = (const u16*)(ws + WS_QUE);  const u16* que_b = (const u16*)(ws + WS_QUEB);
  const u16* a1v_w = (const u16*)(ws + WS_A1V);  const u16* a1v_b = (const u16*)(ws + WS_A1VB);
  const u16* a1o_w = (const u16*)(ws + WS_A1O);  const u16* a1o_b = (const u16*)(ws + WS_A1OB);
  const u16* val_w = (const u16*)(ws + WS_VAL);  const u16* val_b = (const u16*)(ws + WS_VALB);
  const u16* pol_w = (const u16*)(ws + WS_POL);  const u16* pol_b = (const u16*)(ws + WS_POLB);
  const u16* an_g = (const u16*)(ws + WS_ANG);   const u16* an_b = (const u16*)(ws + WS_ANB);
  const u16* fn_g = (const u16*)(ws + WS_FNG);   const u16* fn_b = (const u16*)(ws + WS_FNB);

  if (tid == 0) {  // int64-vs-int32 probe for queue (values are 0..7; int64 high words == 0)
    int odd = 0;
    for (int i = 1; i < 128; i += 2) odd += (queue[i] != 0);
    qs_s = (odd == 0) ? 2 : 1;
  }
  __syncthreads();
  if (tid < 16) piece_s[tid] = queue[(size_t)(r0 + tid) * 5 * qs_s] & 7;
  for (int idx = tid; idx < 16 * 64; idx += 256) {
    const int r = idx >> 6, c = idx & 63;
    *(uint4*)&X[r * LSTR + c * 8] = ((const uint4*)(state16 + (size_t)r0 * 512))[r * 64 + c];
  }
  __syncthreads();

  f32x4 acc[8];
  // L1: v0 = state_in @ a0v^T                      X -> Y
  gemm16(X, a0v_w, a0v_b, wid, lane, acc);
  store_bf(Y, wid, lane, acc);
  __syncthreads();
  // L2: s0 = v0 @ a0o^T                            Y -> X (residual)
  gemm16(Y, a0o_w, a0o_b, wid, lane, acc);
  store_bf(X, wid, lane, acc);
  __syncthreads();
  // L3: qv = s0 @ q_w^T                            X -> Z
  gemm16(X, q_w, q_b, wid, lane, acc);
  store_bf(Z, wid, lane, acc);
  __syncthreads();
  // attention over 4 piece-keys: Z(qv) + kk/vv -> Y
  if (tid < 128) {
    const int r = tid >> 3, h = tid & 7;
    const int p = piece_s[r];
    const u16* qrow = &Z[r * LSTR + h * 64];
    const float* kkp = kk_ws + (size_t)(p * 4) * 512 + h * 64;
    const float* vvp = vv_ws + (size_t)(p * 4) * 512 + h * 64;
    float lg[4];
#pragma unroll
    for (int j = 0; j < 4; ++j) {
      float s = 0.f;
      const float* kj = kkp + j * 512;
#pragma unroll
      for (int d = 0; d < 64; d += 4) {
        const float4 kv = *(const float4*)(kj + d);
        s += bf2f(qrow[d]) * kv.x + bf2f(qrow[d + 1]) * kv.y + bf2f(qrow[d + 2]) * kv.z +
             bf2f(qrow[d + 3]) * kv.w;
      }
      lg[j] = s * 0.125f;  // 1/sqrt(64)
    }
    const float m = fmaxf(fmaxf(lg[0], lg[1]), fmaxf(lg[2], lg[3]));
    float e0 = __expf(lg[0] - m), e1 = __expf(lg[1] - m);
    float e2 = __expf(lg[2] - m), e3 = __expf(lg[3] - m);
    const float inv = 1.f / (e0 + e1 + e2 + e3);
    e0 *= inv; e1 *= inv; e2 *= inv; e3 *= inv;
    u16* orow = &Y[r * LSTR + h * 64];
#pragma unroll
    for (int d = 0; d < 64; d += 4) {
      const float4 v0 = *(const float4*)(vvp + 0 * 512 + d);
      const float4 v1 = *(const float4*)(vvp + 1 * 512 + d);
      const float4 v2 = *(const float4*)(vvp + 2 * 512 + d);
      const float4 v3 = *(const float4*)(vvp + 3 * 512 + d);
      orow[d + 0] = f2bf(e0 * v0.x + e1 * v1.x + e2 * v2.x + e3 * v3.x);
      orow[d + 1] = f2bf(e0 * v0.y + e1 * v1.y + e2 * v2.y + e3 * v3.y);
      orow[d + 2] = f2bf(e0 * v0.z + e1 * v1.z + e2 * v2.z + e3 * v3.z);
      orow[d + 3] = f2bf(e0 * v0.w + e1 * v1.w + e2 * v2.w + e3 * v3.w);
    }
  }
  __syncthreads();
  // L4: x1 = s0 + attn @ qkv^T                     Y -> Z ; LN1 -> Y (s1)
  gemm16(Y, qkv_w, qkv_b, wid, lane, acc);
  add_lds_bf(X, wid, lane, acc);
  store_bf(Z, wid, lane, acc);
  __syncthreads();
  layer_norm_bf(Z, Y, an_g, an_b, tid);
  __syncthreads();
  // L5: x2 = s1 + s1 @ que_w^T                     Y -> Z ; LN2 -> X (s2)
  gemm16(Y, que_w, que_b, wid, lane, acc);
  add_lds_bf(Y, wid, lane, acc);
  store_bf(Z, wid, lane, acc);
  __syncthreads();
  layer_norm_bf(Z, X, fn_g, fn_b, tid);
  __syncthreads();
  // L6: v1 = s2 @ a1v^T                            X -> Y
  gemm16(X, a1v_w, a1v_b, wid, lane, acc);
  store_bf(Y, wid, lane, acc);
  __syncthreads();
  // L7: xo = v1 @ a1o^T + memory                   Y -> X
  gemm16(Y, a1o_w, a1o_b, wid, lane, acc);
  add_glb_bf(mem16 + (size_t)r0 * 512, wid, lane, acc);
  store_bf(X, wid, lane, acc);
  __syncthreads();
  // L8: val = xo @ val_w^T  -> out (f32)
  gemm16(X, val_w, val_b, wid, lane, acc);
  {
    const int cr = lane & 15, rb = (lane >> 4) * 4;
#pragma unroll
    for (int nt = 0; nt < 8; ++nt) {
      const int col = wid * 128 + nt * 16 + cr;
#pragma unroll
      for (int r = 0; r < 4; ++r) out_val[(size_t)(r0 + rb + r) * 512 + col] = acc[nt][r];
    }
  }
  // L9: pol = xo @ pol_w^T (10 cols), wave 0 only
  if (wid == 0) {
    const int rc = lane & 15, kb = lane >> 4;
    const int wrow = rc < 10 ? rc : 0;
    const bf16x8* ab = reinterpret_cast<const bf16x8*>(X) + rc * (LSTR / 8) + kb;
    const bf16x8* wb = reinterpret_cast<const bf16x8*>(pol_w) + wrow * 64 + kb;
    f32x4 pa = (f32x4){0.f, 0.f, 0.f, 0.f};
#pragma unroll
    for (int ks = 0; ks < 16; ++ks) pa = MFMA(ab[ks * 4], wb[ks * 4], pa);
    if (rc < 10) {
      const float bv = bf2f(pol_b[rc]);
      const int rb = (lane >> 4) * 4;
#pragma unroll
      for (int r = 0; r < 4; ++r) out_pol[(size_t)(r0 + rb + r) * 10 + rc] = pa[r] + bv;
    }
  }
}

extern "C" void kernel_launch(void* const* d_in, const int* in_sizes, int n_in, void* d_out,
                              int out_size, void* d_ws, size_t ws_size, hipStream_t stream) {
  (void)in_sizes; (void)n_in; (void)out_size; (void)ws_size;
  char* ws = (char*)d_ws;

  Jobs jobs;
  int ji = 0;
  auto add = [&](int idx, int eoff, int n, int off) {
    jobs.j[ji].base = d_in[idx]; jobs.j[ji].eoff = eoff; jobs.j[ji].n = n;
    jobs.j[ji].dstoff = off; ++ji;
  };
  add(3, 0, 262144, WS_STATE);
  add(38, 524288, 262144, WS_A0V);   // a0_in_w rows [1024:1536]
  add(40, 0, 262144, WS_A0O);
  add(12, 0, 262144, WS_QW);
  add(18, 0, 262144, WS_QKV);
  add(20, 0, 262144, WS_QUE);
  add(42, 524288, 262144, WS_A1V);   // a1_in_w rows [1024:1536]
  add(44, 0, 262144, WS_A1O);
  add(48, 0, 262144, WS_VAL);
  add(46, 0, 5120, WS_POL);
  add(9, 0, 4096, WS_PEMB);
  add(10, 0, 1048576, WS_ROT);
  add(14, 0, 262144, WS_KW);
  add(16, 0, 262144, WS_VW);
  add(4, 0, 262144, WS_MEM);
  add(11, 0, 2048, WS_ROTB);
  add(39, 1024, 512, WS_A0VB);
  add(41, 0, 512, WS_A0OB);
  add(13, 0, 512, WS_QB);
  add(15, 0, 512, WS_KB);
  add(17, 0, 512, WS_VB);
  add(19, 0, 512, WS_QKVB);
  add(21, 0, 512, WS_QUEB);
  add(43, 1024, 512, WS_A1VB);
  add(45, 0, 512, WS_A1OB);
  add(49, 0, 512, WS_VALB);
  add(22, 0, 512, WS_ANG);
  add(23, 0, 512, WS_ANB);
  add(24, 0, 512, WS_FNG);
  add(25, 0, 512, WS_FNB);
  add(47, 0, 10, WS_POLB);

  k_convert<<<dim3(512, 31), dim3(256), 0, stream>>>(jobs, (const u16*)d_in[3], ws);
  k_pieces_rot<<<dim3(16), dim3(256), 0, stream>>>((const u16*)(ws + WS_PEMB),
                                                   (const u16*)(ws + WS_ROT),
                                                   (const u16*)(ws + WS_ROTB),
                                                   (u16*)(ws + WS_PWR));
  k_pieces_kv<<<dim3(8), dim3(256), 0, stream>>>(
      (const u16*)(ws + WS_PWR), (const u16*)(ws + WS_KW), (const u16*)(ws + WS_KB),
      (const u16*)(ws + WS_VW), (const u16*)(ws + WS_VB), (float*)(ws + WS_KK),
      (float*)(ws + WS_VV));

  float* out_pol = (float*)d_out;
  float* out_val = out_pol + 512 * 10;
  k_main<<<dim3(32), dim3(256), 0, stream>>>((const u16*)(ws + WS_STATE),
                                             (const u16*)(ws + WS_MEM), (const int*)d_in[1],
                                             (const char*)ws, (const float*)(ws + WS_KK),
                                             (const float*)(ws + WS_VV), out_pol, out_val);
}

// Round 4
// 173.417 us; speedup vs baseline: 1.4057x; 1.4057x over previous
//
#include <hip/hip_runtime.h>

typedef unsigned short u16;
typedef __attribute__((ext_vector_type(8))) short bf16x8;
typedef __attribute__((ext_vector_type(4))) float f32x4;

#define LSTR 520  // bf16 elems per LDS row: 512 + 8 pad

// ---------------- workspace layout (bytes) ----------------
#define WS_A0V     524288
#define WS_A0O     1048576
#define WS_QW      1572864
#define WS_QKV     2097152
#define WS_QUE     2621440
#define WS_A1V     3145728
#define WS_A1O     3670016
#define WS_VAL     4194304
#define WS_POL     4718592
#define WS_PEMB    4728832
#define WS_ROT     4737024
#define WS_KW      6834176
#define WS_VW      7358464
#define WS_KK      7915520
#define WS_VV      7981056
#define WS_ROTB    8570880
#define WS_A0VB    8574976
#define WS_A0OB    (WS_A0VB + 1024)
#define WS_QB      (WS_A0VB + 2048)
#define WS_KB      (WS_A0VB + 3072)
#define WS_VB      (WS_A0VB + 4096)
#define WS_QKVB    (WS_A0VB + 5120)
#define WS_QUEB    (WS_A0VB + 6144)
#define WS_A1VB    (WS_A0VB + 7168)
#define WS_A1OB    (WS_A0VB + 8192)
#define WS_VALB    (WS_A0VB + 9216)
#define WS_ANG     (WS_A0VB + 10240)
#define WS_ANB     (WS_A0VB + 11264)
#define WS_FNG     (WS_A0VB + 12288)
#define WS_FNB     (WS_A0VB + 13312)
#define WS_POLB    (WS_A0VB + 14336)

__device__ __forceinline__ float bf2f(u16 u) {
  union { unsigned int i; float f; } v; v.i = ((unsigned int)u) << 16; return v.f;
}
__device__ __forceinline__ u16 f2bf(float f) {
  union { float f; unsigned int i; } v; v.f = f;
  unsigned int r = v.i + 0x7fffu + ((v.i >> 16) & 1u);
  return (u16)(r >> 16);
}
__device__ __forceinline__ f32x4 MFMA(bf16x8 a, bf16x8 b, f32x4 c) {
  return __builtin_amdgcn_mfma_f32_16x16x32_bf16(a, b, c, 0, 0, 0);
}

// ---------------- weight staging: f32 -> bf16 ----------------
struct Job { const void* base; int eoff; int n; int dstoff; };
struct Jobs { Job j[29]; };

__global__ __launch_bounds__(256) void k_convert(Jobs jobs, char* __restrict__ ws) {
  const Job jb = jobs.j[blockIdx.y];
  const int i0 = (blockIdx.x * 256 + threadIdx.x) * 8;
  if (i0 >= jb.n) return;
  u16* dst = (u16*)(ws + jb.dstoff);
  const float* src = (const float*)jb.base + jb.eoff;
  if (i0 + 8 <= jb.n) {
    const float4 a = *(const float4*)(src + i0);
    const float4 b = *(const float4*)(src + i0 + 4);
    u16 o[8] = {f2bf(a.x), f2bf(a.y), f2bf(a.z), f2bf(a.w),
                f2bf(b.x), f2bf(b.y), f2bf(b.z), f2bf(b.w)};
    *(uint4*)(dst + i0) = *(uint4*)o;
  } else {
    for (int k = i0; k < jb.n; ++k) dst[k] = f2bf(src[k]);
  }
}

// ---- per-wave GEMM tile (16 waves): Y[16x512] = A(LDS) @ W^T + bias
// wave wid owns cols [wid*32, wid*32+32). MFMA 16x16x32 layouts:
// A: row=lane&15, k=(lane>>4)*8+j ; B: col=lane&15, k same ; D: col=lane&15, row=(lane>>4)*4+reg.
__device__ __forceinline__ void gemmW(const u16* A, const u16* W, const u16* bias,
                                      int wid, int lane, f32x4 acc[2]) {
  const int rc = lane & 15;
  const int kb = lane >> 4;
  const bf16x8* ab = reinterpret_cast<const bf16x8*>(A) + rc * (LSTR / 8) + kb;
  const bf16x8* wb = reinterpret_cast<const bf16x8*>(W) + (wid * 32 + rc) * 64 + kb;
  acc[0] = (f32x4){0.f, 0.f, 0.f, 0.f};
  acc[1] = acc[0];
#pragma unroll
  for (int ks = 0; ks < 16; ++ks) {
    bf16x8 a = ab[ks * 4];
    acc[0] = MFMA(a, wb[ks * 4], acc[0]);
    acc[1] = MFMA(a, wb[1024 + ks * 4], acc[1]);
  }
#pragma unroll
  for (int nt = 0; nt < 2; ++nt) {
    const float bv = bf2f(bias[wid * 32 + nt * 16 + rc]);
#pragma unroll
    for (int r = 0; r < 4; ++r) acc[nt][r] += bv;
  }
}

__device__ __forceinline__ void store_bf(u16* dst, int wid, int lane, const f32x4 acc[2]) {
  const int cr = lane & 15, rb = (lane >> 4) * 4;
#pragma unroll
  for (int nt = 0; nt < 2; ++nt) {
    const int col = wid * 32 + nt * 16 + cr;
#pragma unroll
    for (int r = 0; r < 4; ++r) dst[(rb + r) * LSTR + col] = f2bf(acc[nt][r]);
  }
}

__device__ __forceinline__ void add_lds_bf(const u16* src, int wid, int lane, f32x4 acc[2]) {
  const int cr = lane & 15, rb = (lane >> 4) * 4;
#pragma unroll
  for (int nt = 0; nt < 2; ++nt) {
    const int col = wid * 32 + nt * 16 + cr;
#pragma unroll
    for (int r = 0; r < 4; ++r) acc[nt][r] += bf2f(src[(rb + r) * LSTR + col]);
  }
}

__device__ __forceinline__ void add_glb_f32(const float* g, int wid, int lane, f32x4 acc[2]) {
  const int cr = lane & 15, rb = (lane >> 4) * 4;
#pragma unroll
  for (int nt = 0; nt < 2; ++nt) {
    const int col = wid * 32 + nt * 16 + cr;
#pragma unroll
    for (int r = 0; r < 4; ++r) acc[nt][r] += g[(size_t)(rb + r) * 512 + col];
  }
}

// LayerNorm: wave wid handles row wid; 64 lanes span 512 cols.
__device__ __forceinline__ void layer_norm_bf(const u16* X, u16* dst, const u16* g,
                                              const u16* b, int wid, int lane) {
  float s = 0.f, q = 0.f;
#pragma unroll
  for (int c = lane; c < 512; c += 64) {
    const float v = bf2f(X[wid * LSTR + c]);
    s += v; q += v * v;
  }
#pragma unroll
  for (int m = 1; m < 64; m <<= 1) {
    s += __shfl_xor(s, m, 64);
    q += __shfl_xor(q, m, 64);
  }
  const float mu = s * (1.f / 512.f);
  const float rs = rsqrtf(q * (1.f / 512.f) - mu * mu + 1e-5f);
#pragma unroll
  for (int c = lane; c < 512; c += 64) {
    const float v = (bf2f(X[wid * LSTR + c]) - mu) * rs * bf2f(g[c]) + bf2f(b[c]);
    dst[wid * LSTR + c] = f2bf(v);
  }
}

// ---- piece kernel: 8 blocks = (j in 0..3) x (t in {k,v}).
__global__ __launch_bounds__(1024) void k_pieces(const char* __restrict__ ws,
                                                 float* __restrict__ kk_ws,
                                                 float* __restrict__ vv_ws) {
  __shared__ __align__(16) u16 A[16 * LSTR];
  __shared__ __align__(16) u16 P[16 * LSTR];
  const int tid = threadIdx.x, lane = tid & 63, wid = tid >> 6;
  const int j = blockIdx.x >> 1, t = blockIdx.x & 1;
  const u16* pemb = (const u16*)(ws + WS_PEMB);
  const u16* rot_w = (const u16*)(ws + WS_ROT);
  const u16* rot_b = (const u16*)(ws + WS_ROTB);

  for (int idx = tid; idx < 16 * 64; idx += 1024) {
    const int r = idx >> 6, c = idx & 63;
    uint4 v;
    if (r < 8) v = ((const uint4*)pemb)[r * 64 + c];
    else { v.x = v.y = v.z = v.w = 0u; }
    *(uint4*)&A[r * LSTR + c * 8] = v;
  }
  __syncthreads();

  const int rc = lane & 15, kb = lane >> 4;
  const int cr = lane & 15, rb = (lane >> 4) * 4;
  {
    const bf16x8* ab = reinterpret_cast<const bf16x8*>(A) + rc * (LSTR / 8) + kb;
    const bf16x8* wb =
        reinterpret_cast<const bf16x8*>(rot_w) + ((j * 512) + wid * 32 + rc) * 64 + kb;
    f32x4 a0 = (f32x4){0.f, 0.f, 0.f, 0.f}, a1 = a0;
#pragma unroll
    for (int ks = 0; ks < 16; ++ks) {
      bf16x8 a = ab[ks * 4];
      a0 = MFMA(a, wb[ks * 4], a0);
      a1 = MFMA(a, wb[1024 + ks * 4], a1);
    }
#pragma unroll
    for (int nt = 0; nt < 2; ++nt) {
      const int o = wid * 32 + nt * 16 + cr;
      const float bv = bf2f(rot_b[j * 512 + o]);
#pragma unroll
      for (int r = 0; r < 4; ++r)
        P[(rb + r) * LSTR + o] = f2bf((nt == 0 ? a0[r] : a1[r]) + bv);
    }
  }
  __syncthreads();
  {
    const u16* W = (const u16*)(ws + (t ? WS_VW : WS_KW));
    const u16* Bb = (const u16*)(ws + (t ? WS_VB : WS_KB));
    float* out = t ? vv_ws : kk_ws;
    const bf16x8* ab = reinterpret_cast<const bf16x8*>(P) + rc * (LSTR / 8) + kb;
    const bf16x8* wb = reinterpret_cast<const bf16x8*>(W) + (wid * 32 + rc) * 64 + kb;
    f32x4 a0 = (f32x4){0.f, 0.f, 0.f, 0.f}, a1 = a0;
#pragma unroll
    for (int ks = 0; ks < 16; ++ks) {
      bf16x8 a = ab[ks * 4];
      a0 = MFMA(a, wb[ks * 4], a0);
      a1 = MFMA(a, wb[1024 + ks * 4], a1);
    }
#pragma unroll
    for (int nt = 0; nt < 2; ++nt) {
      const int col = wid * 32 + nt * 16 + cr;
      const float bv = bf2f(Bb[col]);
#pragma unroll
      for (int r = 0; r < 4; ++r) {
        const int p = rb + r;
        if (p < 8) out[(size_t)(p * 4 + j) * 512 + col] = (nt == 0 ? a0[r] : a1[r]) + bv;
      }
    }
  }
}

// ---- main fused chain: 32 blocks x 1024 threads (16 waves), 16 batch rows each.
__global__ __launch_bounds__(1024) void k_main(
    const float* __restrict__ state32, const float* __restrict__ mem32,
    const int* __restrict__ queue, const char* __restrict__ ws,
    const float* __restrict__ kk_ws, const float* __restrict__ vv_ws,
    float* __restrict__ out_pol, float* __restrict__ out_val) {
  __shared__ __align__(16) u16 X[16 * LSTR];
  __shared__ __align__(16) u16 Y[16 * LSTR];
  __shared__ __align__(16) u16 Z[16 * LSTR];
  __shared__ int piece_s[16];
  __shared__ int qs_s;
  const int tid = threadIdx.x;
  const int lane = tid & 63, wid = tid >> 6;
  const int r0 = blockIdx.x * 16;

  const u16* a0v_w = (const u16*)(ws + WS_A0V);  const u16* a0v_b = (const u16*)(ws + WS_A0VB);
  const u16* a0o_w = (const u16*)(ws + WS_A0O);  const u16* a0o_b = (const u16*)(ws + WS_A0OB);
  const u16* q_w   = (const u16*)(ws + WS_QW);   const u16* q_b   = (const u16*)(ws + WS_QB);
  const u16* qkv_w = (const u16*)(ws + WS_QKV);  const u16* qkv_b = (const u16*)(ws + WS_QKVB);
  const u16* que_w = (const u16*)(ws + WS_QUE);  const u16* que_b = (const u16*)(ws + WS_QUEB);
  const u16* a1v_w = (const u16*)(ws + WS_A1V);  const u16* a1v_b = (const u16*)(ws + WS_A1VB);
  const u16* a1o_w = (const u16*)(ws + WS_A1O);  const u16* a1o_b = (const u16*)(ws + WS_A1OB);
  const u16* val_w = (const u16*)(ws + WS_VAL);  const u16* val_b = (const u16*)(ws + WS_VALB);
  const u16* pol_w = (const u16*)(ws + WS_POL);  const u16* pol_b = (const u16*)(ws + WS_POLB);
  const u16* an_g = (const u16*)(ws + WS_ANG);   const u16* an_b = (const u16*)(ws + WS_ANB);
  const u16* fn_g = (const u16*)(ws + WS_FNG);   const u16* fn_b = (const u16*)(ws + WS_FNB);

  // stage state rows (f32 -> bf16 LDS): 1024 threads x 8 elems = 16x512
  {
    const int r = tid >> 6, c8 = (tid & 63) * 8;
    const float* src = state32 + (size_t)(r0 + r) * 512 + c8;
    const float4 a = *(const float4*)src;
    const float4 b = *(const float4*)(src + 4);
    u16 o[8] = {f2bf(a.x), f2bf(a.y), f2bf(a.z), f2bf(a.w),
                f2bf(b.x), f2bf(b.y), f2bf(b.z), f2bf(b.w)};
    *(uint4*)&X[r * LSTR + c8] = *(uint4*)o;
  }
  if (tid == 0) {  // int64-vs-int32 probe (int64: odd u32 words are all zero)
    int odd = 0;
    for (int i = 1; i < 128; i += 2) odd += (queue[i] != 0);
    qs_s = (odd == 0) ? 2 : 1;
  }
  __syncthreads();  // qs_s + X visible to all waves BEFORE any use (round-3 race fix)
  if (tid < 16) piece_s[tid] = queue[(size_t)(r0 + tid) * 5 * qs_s] & 7;
  // piece_s consumed only after the L1..L3 barriers below -> ordering is safe.

  f32x4 acc[2];
  // L1: v0 = state @ a0v^T                         X -> Y
  gemmW(X, a0v_w, a0v_b, wid, lane, acc);
  store_bf(Y, wid, lane, acc);
  __syncthreads();
  // L2: s0 = v0 @ a0o^T                            Y -> X (residual)
  gemmW(Y, a0o_w, a0o_b, wid, lane, acc);
  store_bf(X, wid, lane, acc);
  __syncthreads();
  // L3: qv = s0 @ q_w^T                            X -> Z
  gemmW(X, q_w, q_b, wid, lane, acc);
  store_bf(Z, wid, lane, acc);
  __syncthreads();
  // 4-key attention: Z(qv) + kk/vv -> Y
  if (tid < 128) {
    const int r = tid >> 3, h = tid & 7;
    const int p = piece_s[r];
    const u16* qrow = &Z[r * LSTR + h * 64];
    const float* kkp = kk_ws + (size_t)(p * 4) * 512 + h * 64;
    const float* vvp = vv_ws + (size_t)(p * 4) * 512 + h * 64;
    float lg[4];
#pragma unroll
    for (int jj = 0; jj < 4; ++jj) {
      float s = 0.f;
      const float* kj = kkp + jj * 512;
#pragma unroll
      for (int d = 0; d < 64; d += 4) {
        const float4 kv = *(const float4*)(kj + d);
        s += bf2f(qrow[d]) * kv.x + bf2f(qrow[d + 1]) * kv.y + bf2f(qrow[d + 2]) * kv.z +
             bf2f(qrow[d + 3]) * kv.w;
      }
      lg[jj] = s * 0.125f;
    }
    const float m = fmaxf(fmaxf(lg[0], lg[1]), fmaxf(lg[2], lg[3]));
    float e0 = __expf(lg[0] - m), e1 = __expf(lg[1] - m);
    float e2 = __expf(lg[2] - m), e3 = __expf(lg[3] - m);
    const float inv = 1.f / (e0 + e1 + e2 + e3);
    e0 *= inv; e1 *= inv; e2 *= inv; e3 *= inv;
    u16* orow = &Y[r * LSTR + h * 64];
#pragma unroll
    for (int d = 0; d < 64; d += 4) {
      const float4 v0 = *(const float4*)(vvp + 0 * 512 + d);
      const float4 v1 = *(const float4*)(vvp + 1 * 512 + d);
      const float4 v2 = *(const float4*)(vvp + 2 * 512 + d);
      const float4 v3 = *(const float4*)(vvp + 3 * 512 + d);
      orow[d + 0] = f2bf(e0 * v0.x + e1 * v1.x + e2 * v2.x + e3 * v3.x);
      orow[d + 1] = f2bf(e0 * v0.y + e1 * v1.y + e2 * v2.y + e3 * v3.y);
      orow[d + 2] = f2bf(e0 * v0.z + e1 * v1.z + e2 * v2.z + e3 * v3.z);
      orow[d + 3] = f2bf(e0 * v0.w + e1 * v1.w + e2 * v2.w + e3 * v3.w);
    }
  }
  __syncthreads();
  // L4: x1 = s0 + attn @ qkv^T                     Y -> Z ; LN1 -> Y (s1)
  gemmW(Y, qkv_w, qkv_b, wid, lane, acc);
  add_lds_bf(X, wid, lane, acc);
  store_bf(Z, wid, lane, acc);
  __syncthreads();
  layer_norm_bf(Z, Y, an_g, an_b, wid, lane);
  __syncthreads();
  // L5: x2 = s1 + s1 @ que_w^T                     Y -> Z ; LN2 -> X (s2)
  gemmW(Y, que_w, que_b, wid, lane, acc);
  add_lds_bf(Y, wid, lane, acc);
  store_bf(Z, wid, lane, acc);
  __syncthreads();
  layer_norm_bf(Z, X, fn_g, fn_b, wid, lane);
  __syncthreads();
  // L6: v1 = s2 @ a1v^T                            X -> Y
  gemmW(X, a1v_w, a1v_b, wid, lane, acc);
  store_bf(Y, wid, lane, acc);
  __syncthreads();
  // L7: xo = v1 @ a1o^T + memory                   Y -> X
  gemmW(Y, a1o_w, a1o_b, wid, lane, acc);
  add_glb_f32(mem32 + (size_t)r0 * 512, wid, lane, acc);
  store_bf(X, wid, lane, acc);
  __syncthreads();
  // L8: val = xo @ val_w^T -> out (f32)
  gemmW(X, val_w, val_b, wid, lane, acc);
  {
    const int cr = lane & 15, rb = (lane >> 4) * 4;
#pragma unroll
    for (int nt = 0; nt < 2; ++nt) {
      const int col = wid * 32 + nt * 16 + cr;
#pragma unroll
      for (int r = 0; r < 4; ++r) out_val[(size_t)(r0 + rb + r) * 512 + col] = acc[nt][r];
    }
  }
  // L9: pol = xo @ pol_w^T (10 cols), wave 0 only
  if (wid == 0) {
    const int rc = lane & 15, kb = lane >> 4;
    const int wrow = rc < 10 ? rc : 0;
    const bf16x8* ab = reinterpret_cast<const bf16x8*>(X) + rc * (LSTR / 8) + kb;
    const bf16x8* wb = reinterpret_cast<const bf16x8*>(pol_w) + wrow * 64 + kb;
    f32x4 pa = (f32x4){0.f, 0.f, 0.f, 0.f};
#pragma unroll
    for (int ks = 0; ks < 16; ++ks) pa = MFMA(ab[ks * 4], wb[ks * 4], pa);
    if (rc < 10) {
      const float bv = bf2f(pol_b[rc]);
      const int rb = (lane >> 4) * 4;
#pragma unroll
      for (int r = 0; r < 4; ++r) out_pol[(size_t)(r0 + rb + r) * 10 + rc] = pa[r] + bv;
    }
  }
}

extern "C" void kernel_launch(void* const* d_in, const int* in_sizes, int n_in, void* d_out,
                              int out_size, void* d_ws, size_t ws_size, hipStream_t stream) {
  (void)in_sizes; (void)n_in; (void)out_size; (void)ws_size;
  char* ws = (char*)d_ws;

  Jobs jobs;
  int ji = 0;
  auto add = [&](int idx, int eoff, int n, int off) {
    jobs.j[ji].base = d_in[idx]; jobs.j[ji].eoff = eoff; jobs.j[ji].n = n;
    jobs.j[ji].dstoff = off; ++ji;
  };
  add(38, 524288, 262144, WS_A0V);   // a0_in_w rows [1024:1536]
  add(40, 0, 262144, WS_A0O);
  add(12, 0, 262144, WS_QW);
  add(18, 0, 262144, WS_QKV);
  add(20, 0, 262144, WS_QUE);
  add(42, 524288, 262144, WS_A1V);   // a1_in_w rows [1024:1536]
  add(44, 0, 262144, WS_A1O);
  add(48, 0, 262144, WS_VAL);
  add(46, 0, 5120, WS_POL);
  add(9, 0, 4096, WS_PEMB);
  add(10, 0, 1048576, WS_ROT);
  add(14, 0, 262144, WS_KW);
  add(16, 0, 262144, WS_VW);
  add(11, 0, 2048, WS_ROTB);
  add(39, 1024, 512, WS_A0VB);
  add(41, 0, 512, WS_A0OB);
  add(13, 0, 512, WS_QB);
  add(15, 0, 512, WS_KB);
  add(17, 0, 512, WS_VB);
  add(19, 0, 512, WS_QKVB);
  add(21, 0, 512, WS_QUEB);
  add(43, 1024, 512, WS_A1VB);
  add(45, 0, 512, WS_A1OB);
  add(49, 0, 512, WS_VALB);
  add(22, 0, 512, WS_ANG);
  add(23, 0, 512, WS_ANB);
  add(24, 0, 512, WS_FNG);
  add(25, 0, 512, WS_FNB);
  add(47, 0, 10, WS_POLB);

  k_convert<<<dim3(512, 29), dim3(256), 0, stream>>>(jobs, ws);
  k_pieces<<<dim3(8), dim3(1024), 0, stream>>>(ws, (float*)(ws + WS_KK), (float*)(ws + WS_VV));

  float* out_pol = (float*)d_out;
  float* out_val = out_pol + 512 * 10;
  k_main<<<dim3(32), dim3(1024), 0, stream>>>(
      (const float*)d_in[3], (const float*)d_in[4], (const int*)d_in[1], (const char*)ws,
      (const float*)(ws + WS_KK), (const float*)(ws + WS_VV), out_pol, out_val);
}

// Round 5
// 98.380 us; speedup vs baseline: 2.4779x; 1.7627x over previous
//
#include <hip/hip_runtime.h>

typedef unsigned short u16;
typedef __attribute__((ext_vector_type(8))) short bf16x8;
typedef __attribute__((ext_vector_type(4))) float f32x4;

#define LSTR 520  // bf16 elems per LDS row: 512 + 8 pad

// ---------------- workspace layout (bytes) ----------------
// main GEMM weights (chunked layout, 512 KB each)
#define WS_A0V     524288
#define WS_A0O     1048576
#define WS_QW      1572864
#define WS_QKV     2097152
#define WS_QUE     2621440
#define WS_A1V     3145728
#define WS_A1O     3670016
#define WS_VAL     4194304
// plain-layout tensors
#define WS_POL     4718592
#define WS_PEMB    4728832
#define WS_ROT     4737024
#define WS_KW      6834176
#define WS_VW      7358464
#define WS_PWR     7882752
#define WS_KK      7915520
#define WS_VV      7981056
#define WS_ROTB    8570880
#define WS_A0VB    8574976
#define WS_A0OB    (WS_A0VB + 1024)
#define WS_QB      (WS_A0VB + 2048)
#define WS_KB      (WS_A0VB + 3072)
#define WS_VB      (WS_A0VB + 4096)
#define WS_QKVB    (WS_A0VB + 5120)
#define WS_QUEB    (WS_A0VB + 6144)
#define WS_A1VB    (WS_A0VB + 7168)
#define WS_A1OB    (WS_A0VB + 8192)
#define WS_VALB    (WS_A0VB + 9216)
#define WS_ANG     (WS_A0VB + 10240)
#define WS_ANB     (WS_A0VB + 11264)
#define WS_FNG     (WS_A0VB + 12288)
#define WS_FNB     (WS_A0VB + 13312)
#define WS_POLB    (WS_A0VB + 14336)

__device__ __forceinline__ float bf2f(u16 u) {
  union { unsigned int i; float f; } v; v.i = ((unsigned int)u) << 16; return v.f;
}
__device__ __forceinline__ u16 f2bf(float f) {
  union { float f; unsigned int i; } v; v.f = f;
  unsigned int r = v.i + 0x7fffu + ((v.i >> 16) & 1u);
  return (u16)(r >> 16);
}
__device__ __forceinline__ f32x4 MFMA(bf16x8 a, bf16x8 b, f32x4 c) {
  return __builtin_amdgcn_mfma_f32_16x16x32_bf16(a, b, c, 0, 0, 0);
}
__device__ __forceinline__ void gl_lds16(const void* g, void* l) {
  __builtin_amdgcn_global_load_lds((const __attribute__((address_space(1))) void*)g,
                                   (__attribute__((address_space(3))) void*)l, 16, 0, 0);
}

// ---------------- staging / conversion ----------------
// mode 0: plain f32->bf16. mode 1: chunked for 512x512 weights:
// elem (col,k) -> chunk c=k>>5, kblk=(k>>3)&3, dst elem = c*16384 + kblk*4096 + col*8 + (k&7)
struct Job { const void* base; int eoff; int n; int dstoff; int mode; };
struct Jobs { Job j[29]; };

__global__ __launch_bounds__(256) void k_convert(Jobs jobs, char* __restrict__ ws) {
  const Job jb = jobs.j[blockIdx.y];
  const int i0 = (blockIdx.x * 256 + threadIdx.x) * 8;
  if (i0 >= jb.n) return;
  u16* dst = (u16*)(ws + jb.dstoff);
  const float* src = (const float*)jb.base + jb.eoff;
  if (i0 + 8 <= jb.n) {
    const float4 a = *(const float4*)(src + i0);
    const float4 b = *(const float4*)(src + i0 + 4);
    u16 o[8] = {f2bf(a.x), f2bf(a.y), f2bf(a.z), f2bf(a.w),
                f2bf(b.x), f2bf(b.y), f2bf(b.z), f2bf(b.w)};
    int off = i0;
    if (jb.mode == 1) {
      const int col = i0 >> 9, k0 = i0 & 511;
      off = (k0 >> 5) * 16384 + ((k0 >> 3) & 3) * 4096 + col * 8;
    }
    *(uint4*)(dst + off) = *(uint4*)o;
  } else {
    for (int k = i0; k < jb.n; ++k) dst[k] = f2bf(src[k]);  // only plain small tails
  }
}

// ---- streamed GEMM layer for k_main (1024 thr = 16 waves, rows=16, cols=512).
// W in chunked layout: 16 chunks x 32KB; chunk c = K-slice [c*32,c*32+32) as [kblk][col][8].
// Double-buffered global_load_lds pipeline, counted vmcnt, raw barriers.
// Ledger: each wave stages 2KB/chunk (2 calls). Iter c: issue stage(c+1) -> outstanding<=4;
// vmcnt(2) -> own chunk-c calls done; s_barrier -> ALL waves' chunk-c staged; ds_read+MFMA
// (compiler lgkmcnt before MFMA => reads complete before...); s_barrier -> all reads of
// buf[c&1] done, safe to restage it at iter c+1.
__device__ __forceinline__ void stage32k(const char* gsrc, u16* lbuf, int wid, int lane) {
  const char* g = gsrc + wid * 2048 + lane * 16;
  u16* l = lbuf + wid * 1024;  // wave-uniform base; lane*16B added by HW
  gl_lds16(g, l);
  gl_lds16(g + 1024, l + 512);
}

__device__ __forceinline__ void gemm_stream(const u16* Xlds, const char* Wg,
                                            u16 (*__restrict__ WB)[16384], const u16* bias,
                                            int wid, int lane, f32x4 acc[2]) {
  const int rc = lane & 15, kb = lane >> 4;
  stage32k(Wg, WB[0], wid, lane);
  acc[0] = (f32x4){0.f, 0.f, 0.f, 0.f};
  acc[1] = acc[0];
#pragma unroll
  for (int c = 0; c < 16; ++c) {
    if (c < 15) {
      stage32k(Wg + (c + 1) * 32768, WB[(c + 1) & 1], wid, lane);
      asm volatile("s_waitcnt vmcnt(2)" ::: "memory");
    } else {
      asm volatile("s_waitcnt vmcnt(0)" ::: "memory");
    }
    __builtin_amdgcn_sched_barrier(0);
    __builtin_amdgcn_s_barrier();
    const u16* B = WB[c & 1];
    const bf16x8 a = *(const bf16x8*)&Xlds[rc * LSTR + c * 32 + kb * 8];
    const bf16x8 b0 = *(const bf16x8*)&B[kb * 4096 + (wid * 32 + rc) * 8];
    const bf16x8 b1 = *(const bf16x8*)&B[kb * 4096 + (wid * 32 + 16 + rc) * 8];
    acc[0] = MFMA(a, b0, acc[0]);
    acc[1] = MFMA(a, b1, acc[1]);
    __builtin_amdgcn_sched_barrier(0);
    __builtin_amdgcn_s_barrier();
  }
#pragma unroll
  for (int nt = 0; nt < 2; ++nt) {
    const float bv = bf2f(bias[wid * 32 + nt * 16 + rc]);
#pragma unroll
    for (int r = 0; r < 4; ++r) acc[nt][r] += bv;
  }
}

__device__ __forceinline__ void store_bf(u16* dst, int wid, int lane, const f32x4 acc[2]) {
  const int cr = lane & 15, rb = (lane >> 4) * 4;
#pragma unroll
  for (int nt = 0; nt < 2; ++nt) {
    const int col = wid * 32 + nt * 16 + cr;
#pragma unroll
    for (int r = 0; r < 4; ++r) dst[(rb + r) * LSTR + col] = f2bf(acc[nt][r]);
  }
}

__device__ __forceinline__ void add_lds_bf(const u16* src, int wid, int lane, f32x4 acc[2]) {
  const int cr = lane & 15, rb = (lane >> 4) * 4;
#pragma unroll
  for (int nt = 0; nt < 2; ++nt) {
    const int col = wid * 32 + nt * 16 + cr;
#pragma unroll
    for (int r = 0; r < 4; ++r) acc[nt][r] += bf2f(src[(rb + r) * LSTR + col]);
  }
}

__device__ __forceinline__ void add_glb_f32(const float* g, int wid, int lane, f32x4 acc[2]) {
  const int cr = lane & 15, rb = (lane >> 4) * 4;
#pragma unroll
  for (int nt = 0; nt < 2; ++nt) {
    const int col = wid * 32 + nt * 16 + cr;
#pragma unroll
    for (int r = 0; r < 4; ++r) acc[nt][r] += g[(size_t)(rb + r) * 512 + col];
  }
}

__device__ __forceinline__ void layer_norm_bf(const u16* X, u16* dst, const u16* g,
                                              const u16* b, int wid, int lane) {
  float s = 0.f, q = 0.f;
#pragma unroll
  for (int c = lane; c < 512; c += 64) {
    const float v = bf2f(X[wid * LSTR + c]);
    s += v; q += v * v;
  }
#pragma unroll
  for (int m = 1; m < 64; m <<= 1) {
    s += __shfl_xor(s, m, 64);
    q += __shfl_xor(q, m, 64);
  }
  const float mu = s * (1.f / 512.f);
  const float rs = rsqrtf(q * (1.f / 512.f) - mu * mu + 1e-5f);
#pragma unroll
  for (int c = lane; c < 512; c += 64) {
    const float v = (bf2f(X[wid * LSTR + c]) - mu) * rs * bf2f(g[c]) + bf2f(b[c]);
    dst[wid * LSTR + c] = f2bf(v);
  }
}

// ---- k_prot: pwr[p*4+j][col] for 8 pieces. 32 blocks = j(4) x colgrp(8), 256 thr.
__global__ __launch_bounds__(256) void k_prot(const char* __restrict__ ws,
                                              u16* __restrict__ pwr_ws) {
  __shared__ __align__(16) u16 A[16 * LSTR];
  const int tid = threadIdx.x, lane = tid & 63, wid = tid >> 6;
  const int j = blockIdx.x >> 3, g = blockIdx.x & 7;
  const u16* pemb = (const u16*)(ws + WS_PEMB);
  const u16* rot_w = (const u16*)(ws + WS_ROT);
  const u16* rot_b = (const u16*)(ws + WS_ROTB);
  for (int idx = tid; idx < 16 * 64; idx += 256) {
    const int r = idx >> 6, c = idx & 63;
    uint4 v;
    if (r < 8) v = ((const uint4*)pemb)[r * 64 + c];
    else { v.x = v.y = v.z = v.w = 0u; }
    *(uint4*)&A[r * LSTR + c * 8] = v;
  }
  __syncthreads();
  const int rc = lane & 15, kb = lane >> 4, rb = (lane >> 4) * 4;
  const int col = g * 64 + wid * 16 + rc;            // 0..511
  const bf16x8* ab = reinterpret_cast<const bf16x8*>(A) + rc * (LSTR / 8) + kb;
  const bf16x8* wb = reinterpret_cast<const bf16x8*>(rot_w) + ((size_t)(j * 512 + col)) * 64 + kb;
  f32x4 acc = (f32x4){0.f, 0.f, 0.f, 0.f};
#pragma unroll
  for (int ks = 0; ks < 16; ++ks) acc = MFMA(ab[ks * 4], wb[ks * 4], acc);
  const float bv = bf2f(rot_b[j * 512 + col]);
#pragma unroll
  for (int r = 0; r < 4; ++r) {
    const int p = rb + r;
    if (p < 8) pwr_ws[(size_t)(p * 4 + j) * 512 + col] = f2bf(acc[r] + bv);
  }
}

// ---- k_pkv: kk/vv[32][512] f32. 32 blocks = t(2) x colgrp(16), 256 thr.
__global__ __launch_bounds__(256) void k_pkv(const char* __restrict__ ws,
                                             const u16* __restrict__ pwr_ws,
                                             float* __restrict__ kk_ws,
                                             float* __restrict__ vv_ws) {
  __shared__ __align__(16) u16 A[32 * LSTR];
  const int tid = threadIdx.x, lane = tid & 63, wid = tid >> 6;
  const int t = blockIdx.x >> 4, g = blockIdx.x & 15;
  for (int idx = tid; idx < 32 * 64; idx += 256) {
    const int r = idx >> 6, c = idx & 63;
    *(uint4*)&A[r * LSTR + c * 8] = ((const uint4*)pwr_ws)[r * 64 + c];
  }
  __syncthreads();
  const u16* W = (const u16*)(ws + (t ? WS_VW : WS_KW));
  const u16* Bb = (const u16*)(ws + (t ? WS_VB : WS_KB));
  float* out = t ? vv_ws : kk_ws;
  const int rc = lane & 15, kb = lane >> 4, rb = (lane >> 4) * 4;
  const int rowt = wid >> 1;                          // 0/1 -> rows rowt*16..
  const int col = g * 32 + (wid & 1) * 16 + rc;       // 0..511
  const bf16x8* ab = reinterpret_cast<const bf16x8*>(A) + (rowt * 16 + rc) * (LSTR / 8) + kb;
  const bf16x8* wb = reinterpret_cast<const bf16x8*>(W) + (size_t)col * 64 + kb;
  f32x4 acc = (f32x4){0.f, 0.f, 0.f, 0.f};
#pragma unroll
  for (int ks = 0; ks < 16; ++ks) acc = MFMA(ab[ks * 4], wb[ks * 4], acc);
  const float bv = bf2f(Bb[col]);
#pragma unroll
  for (int r = 0; r < 4; ++r)
    out[(size_t)(rowt * 16 + rb + r) * 512 + col] = acc[r] + bv;
}

// ---- main fused chain: 32 blocks x 1024 threads (16 waves), 16 batch rows each.
__global__ __launch_bounds__(1024) void k_main(
    const float* __restrict__ state32, const float* __restrict__ mem32,
    const int* __restrict__ queue, const char* __restrict__ ws,
    const float* __restrict__ kk_ws, const float* __restrict__ vv_ws,
    float* __restrict__ out_pol, float* __restrict__ out_val) {
  __shared__ __align__(16) u16 X[16 * LSTR];
  __shared__ __align__(16) u16 Y[16 * LSTR];
  __shared__ __align__(16) u16 Z[16 * LSTR];
  __shared__ __align__(16) u16 WB[2][16384];  // 2 x 32KB weight chunks
  __shared__ int piece_s[16];
  __shared__ int qs_s;
  const int tid = threadIdx.x;
  const int lane = tid & 63, wid = tid >> 6;
  const int r0 = blockIdx.x * 16;

  const u16* a0v_b = (const u16*)(ws + WS_A0VB);
  const u16* a0o_b = (const u16*)(ws + WS_A0OB);
  const u16* q_b   = (const u16*)(ws + WS_QB);
  const u16* qkv_b = (const u16*)(ws + WS_QKVB);
  const u16* que_b = (const u16*)(ws + WS_QUEB);
  const u16* a1v_b = (const u16*)(ws + WS_A1VB);
  const u16* a1o_b = (const u16*)(ws + WS_A1OB);
  const u16* val_b = (const u16*)(ws + WS_VALB);
  const u16* pol_w = (const u16*)(ws + WS_POL);  const u16* pol_b = (const u16*)(ws + WS_POLB);
  const u16* an_g = (const u16*)(ws + WS_ANG);   const u16* an_b = (const u16*)(ws + WS_ANB);
  const u16* fn_g = (const u16*)(ws + WS_FNG);   const u16* fn_b = (const u16*)(ws + WS_FNB);

  // stage state rows (f32 -> bf16 LDS): 1024 threads x 8 elems = 16x512
  {
    const int r = tid >> 6, c8 = (tid & 63) * 8;
    const float* src = state32 + (size_t)(r0 + r) * 512 + c8;
    const float4 a = *(const float4*)src;
    const float4 b = *(const float4*)(src + 4);
    u16 o[8] = {f2bf(a.x), f2bf(a.y), f2bf(a.z), f2bf(a.w),
                f2bf(b.x), f2bf(b.y), f2bf(b.z), f2bf(b.w)};
    *(uint4*)&X[r * LSTR + c8] = *(uint4*)o;
  }
  if (tid == 0) {  // int64-vs-int32 probe (int64: odd u32 words all zero)
    int odd = 0;
    for (int i = 1; i < 128; i += 2) odd += (queue[i] != 0);
    qs_s = (odd == 0) ? 2 : 1;
  }
  __syncthreads();  // X + qs_s visible before use
  if (tid < 16) piece_s[tid] = queue[(size_t)(r0 + tid) * 5 * qs_s] & 7;
  // piece_s consumed after the L1..L3 barriers below.

  f32x4 acc[2];
  // L1: v0 = state @ a0v^T                         X -> Y
  gemm_stream(X, ws + WS_A0V, WB, a0v_b, wid, lane, acc);
  store_bf(Y, wid, lane, acc);
  __syncthreads();
  // L2: s0 = v0 @ a0o^T                            Y -> X (residual)
  gemm_stream(Y, ws + WS_A0O, WB, a0o_b, wid, lane, acc);
  store_bf(X, wid, lane, acc);
  __syncthreads();
  // L3: qv = s0 @ q_w^T                            X -> Z
  gemm_stream(X, ws + WS_QW, WB, q_b, wid, lane, acc);
  store_bf(Z, wid, lane, acc);
  __syncthreads();
  // 4-key attention: Z(qv) + kk/vv -> Y
  if (tid < 128) {
    const int r = tid >> 3, h = tid & 7;
    const int p = piece_s[r];
    const u16* qrow = &Z[r * LSTR + h * 64];
    const float* kkp = kk_ws + (size_t)(p * 4) * 512 + h * 64;
    const float* vvp = vv_ws + (size_t)(p * 4) * 512 + h * 64;
    float lg[4];
#pragma unroll
    for (int jj = 0; jj < 4; ++jj) {
      float s = 0.f;
      const float* kj = kkp + jj * 512;
#pragma unroll
      for (int d = 0; d < 64; d += 4) {
        const float4 kv = *(const float4*)(kj + d);
        s += bf2f(qrow[d]) * kv.x + bf2f(qrow[d + 1]) * kv.y + bf2f(qrow[d + 2]) * kv.z +
             bf2f(qrow[d + 3]) * kv.w;
      }
      lg[jj] = s * 0.125f;
    }
    const float m = fmaxf(fmaxf(lg[0], lg[1]), fmaxf(lg[2], lg[3]));
    float e0 = __expf(lg[0] - m), e1 = __expf(lg[1] - m);
    float e2 = __expf(lg[2] - m), e3 = __expf(lg[3] - m);
    const float inv = 1.f / (e0 + e1 + e2 + e3);
    e0 *= inv; e1 *= inv; e2 *= inv; e3 *= inv;
    u16* orow = &Y[r * LSTR + h * 64];
#pragma unroll
    for (int d = 0; d < 64; d += 4) {
      const float4 v0 = *(const float4*)(vvp + 0 * 512 + d);
      const float4 v1 = *(const float4*)(vvp + 1 * 512 + d);
      const float4 v2 = *(const float4*)(vvp + 2 * 512 + d);
      const float4 v3 = *(const float4*)(vvp + 3 * 512 + d);
      orow[d + 0] = f2bf(e0 * v0.x + e1 * v1.x + e2 * v2.x + e3 * v3.x);
      orow[d + 1] = f2bf(e0 * v0.y + e1 * v1.y + e2 * v2.y + e3 * v3.y);
      orow[d + 2] = f2bf(e0 * v0.z + e1 * v1.z + e2 * v2.z + e3 * v3.z);
      orow[d + 3] = f2bf(e0 * v0.w + e1 * v1.w + e2 * v2.w + e3 * v3.w);
    }
  }
  __syncthreads();
  // L4: x1 = s0 + attn @ qkv^T                     Y -> Z ; LN1 -> Y (s1)
  gemm_stream(Y, ws + WS_QKV, WB, qkv_b, wid, lane, acc);
  add_lds_bf(X, wid, lane, acc);
  store_bf(Z, wid, lane, acc);
  __syncthreads();
  layer_norm_bf(Z, Y, an_g, an_b, wid, lane);
  __syncthreads();
  // L5: x2 = s1 + s1 @ que_w^T                     Y -> Z ; LN2 -> X (s2)
  gemm_stream(Y, ws + WS_QUE, WB, que_b, wid, lane, acc);
  add_lds_bf(Y, wid, lane, acc);
  store_bf(Z, wid, lane, acc);
  __syncthreads();
  layer_norm_bf(Z, X, fn_g, fn_b, wid, lane);
  __syncthreads();
  // L6: v1 = s2 @ a1v^T                            X -> Y
  gemm_stream(X, ws + WS_A1V, WB, a1v_b, wid, lane, acc);
  store_bf(Y, wid, lane, acc);
  __syncthreads();
  // L7: xo = v1 @ a1o^T + memory                   Y -> X
  gemm_stream(Y, ws + WS_A1O, WB, a1o_b, wid, lane, acc);
  add_glb_f32(mem32 + (size_t)r0 * 512, wid, lane, acc);
  store_bf(X, wid, lane, acc);
  __syncthreads();
  // L8: val = xo @ val_w^T -> out (f32)
  gemm_stream(X, ws + WS_VAL, WB, val_b, wid, lane, acc);
  {
    const int cr = lane & 15, rb = (lane >> 4) * 4;
#pragma unroll
    for (int nt = 0; nt < 2; ++nt) {
      const int col = wid * 32 + nt * 16 + cr;
#pragma unroll
      for (int r = 0; r < 4; ++r) out_val[(size_t)(r0 + rb + r) * 512 + col] = acc[nt][r];
    }
  }
  // L9: pol = xo @ pol_w^T (10 cols), wave 0 only
  if (wid == 0) {
    const int rc = lane & 15, kb = lane >> 4;
    const int wrow = rc < 10 ? rc : 0;
    const bf16x8* ab = reinterpret_cast<const bf16x8*>(X) + rc * (LSTR / 8) + kb;
    const bf16x8* wb = reinterpret_cast<const bf16x8*>(pol_w) + wrow * 64 + kb;
    f32x4 pa = (f32x4){0.f, 0.f, 0.f, 0.f};
#pragma unroll
    for (int ks = 0; ks < 16; ++ks) pa = MFMA(ab[ks * 4], wb[ks * 4], pa);
    if (rc < 10) {
      const float bv = bf2f(pol_b[rc]);
      const int rb = (lane >> 4) * 4;
#pragma unroll
      for (int r = 0; r < 4; ++r) out_pol[(size_t)(r0 + rb + r) * 10 + rc] = pa[r] + bv;
    }
  }
}

extern "C" void kernel_launch(void* const* d_in, const int* in_sizes, int n_in, void* d_out,
                              int out_size, void* d_ws, size_t ws_size, hipStream_t stream) {
  (void)in_sizes; (void)n_in; (void)out_size; (void)ws_size;
  char* ws = (char*)d_ws;

  Jobs jobs;
  int ji = 0;
  auto add = [&](int idx, int eoff, int n, int off, int mode) {
    jobs.j[ji].base = d_in[idx]; jobs.j[ji].eoff = eoff; jobs.j[ji].n = n;
    jobs.j[ji].dstoff = off; jobs.j[ji].mode = mode; ++ji;
  };
  add(38, 524288, 262144, WS_A0V, 1);   // a0_in_w rows [1024:1536] (v-slice)
  add(40, 0, 262144, WS_A0O, 1);
  add(12, 0, 262144, WS_QW, 1);
  add(18, 0, 262144, WS_QKV, 1);
  add(20, 0, 262144, WS_QUE, 1);
  add(42, 524288, 262144, WS_A1V, 1);   // a1_in_w rows [1024:1536]
  add(44, 0, 262144, WS_A1O, 1);
  add(48, 0, 262144, WS_VAL, 1);
  add(46, 0, 5120, WS_POL, 0);
  add(9, 0, 4096, WS_PEMB, 0);
  add(10, 0, 1048576, WS_ROT, 0);
  add(14, 0, 262144, WS_KW, 0);
  add(16, 0, 262144, WS_VW, 0);
  add(11, 0, 2048, WS_ROTB, 0);
  add(39, 1024, 512, WS_A0VB, 0);
  add(41, 0, 512, WS_A0OB, 0);
  add(13, 0, 512, WS_QB, 0);
  add(15, 0, 512, WS_KB, 0);
  add(17, 0, 512, WS_VB, 0);
  add(19, 0, 512, WS_QKVB, 0);
  add(21, 0, 512, WS_QUEB, 0);
  add(43, 1024, 512, WS_A1VB, 0);
  add(45, 0, 512, WS_A1OB, 0);
  add(49, 0, 512, WS_VALB, 0);
  add(22, 0, 512, WS_ANG, 0);
  add(23, 0, 512, WS_ANB, 0);
  add(24, 0, 512, WS_FNG, 0);
  add(25, 0, 512, WS_FNB, 0);
  add(47, 0, 10, WS_POLB, 0);

  k_convert<<<dim3(512, 29), dim3(256), 0, stream>>>(jobs, ws);
  k_prot<<<dim3(32), dim3(256), 0, stream>>>(ws, (u16*)(ws + WS_PWR));
  k_pkv<<<dim3(32), dim3(256), 0, stream>>>(ws, (const u16*)(ws + WS_PWR),
                                            (float*)(ws + WS_KK), (float*)(ws + WS_VV));

  float* out_pol = (float*)d_out;
  float* out_val = out_pol + 512 * 10;
  k_main<<<dim3(32), dim3(1024), 0, stream>>>(
      (const float*)d_in[3], (const float*)d_in[4], (const int*)d_in[1], (const char*)ws,
      (const float*)(ws + WS_KK), (const float*)(ws + WS_VV), out_pol, out_val);
}

// Round 6
// 90.384 us; speedup vs baseline: 2.6971x; 1.0885x over previous
//
#include <hip/hip_runtime.h>

typedef unsigned short u16;
typedef __attribute__((ext_vector_type(8))) short bf16x8;
typedef __attribute__((ext_vector_type(4))) float f32x4;

#define LSTR 520  // bf16 elems per LDS row: 512 + 8 pad
#define CH 32768  // weight chunk bytes (K-slice of 32 x 512 cols)

// ---------------- workspace layout (bytes) ----------------
#define WS_A0V     524288
#define WS_A0O     1048576
#define WS_QW      1572864
#define WS_QKV     2097152
#define WS_QUE     2621440
#define WS_A1V     3145728
#define WS_A1O     3670016
#define WS_VAL     4194304
#define WS_POL     4718592
#define WS_PEMB    4728832
#define WS_ROT     4737024
#define WS_KW      6834176
#define WS_VW      7358464
#define WS_PWR     7882752
#define WS_KK      7915520
#define WS_VV      7981056
#define WS_ROTB    8570880
#define WS_A0VB    8574976
#define WS_A0OB    (WS_A0VB + 1024)
#define WS_QB      (WS_A0VB + 2048)
#define WS_KB      (WS_A0VB + 3072)
#define WS_VB      (WS_A0VB + 4096)
#define WS_QKVB    (WS_A0VB + 5120)
#define WS_QUEB    (WS_A0VB + 6144)
#define WS_A1VB    (WS_A0VB + 7168)
#define WS_A1OB    (WS_A0VB + 8192)
#define WS_VALB    (WS_A0VB + 9216)
#define WS_ANG     (WS_A0VB + 10240)
#define WS_ANB     (WS_A0VB + 11264)
#define WS_FNG     (WS_A0VB + 12288)
#define WS_FNB     (WS_A0VB + 13312)
#define WS_POLB    (WS_A0VB + 14336)

__device__ __forceinline__ float bf2f(u16 u) {
  union { unsigned int i; float f; } v; v.i = ((unsigned int)u) << 16; return v.f;
}
__device__ __forceinline__ u16 f2bf(float f) {
  union { float f; unsigned int i; } v; v.f = f;
  unsigned int r = v.i + 0x7fffu + ((v.i >> 16) & 1u);
  return (u16)(r >> 16);
}
__device__ __forceinline__ f32x4 MFMA(bf16x8 a, bf16x8 b, f32x4 c) {
  return __builtin_amdgcn_mfma_f32_16x16x32_bf16(a, b, c, 0, 0, 0);
}
__device__ __forceinline__ void gl_lds16(const void* g, void* l) {
  __builtin_amdgcn_global_load_lds((const __attribute__((address_space(1))) void*)g,
                                   (__attribute__((address_space(3))) void*)l, 16, 0, 0);
}
// exec barrier with LDS-write visibility, WITHOUT vmcnt drain (keeps DMA stream alive)
__device__ __forceinline__ void LBAR() {
  asm volatile("s_waitcnt lgkmcnt(0)" ::: "memory");
  __builtin_amdgcn_sched_barrier(0);
  __builtin_amdgcn_s_barrier();
  __builtin_amdgcn_sched_barrier(0);
}

// ---------------- staging / conversion ----------------
// mode 0: plain f32->bf16. mode 1: chunked for 512x512 weights:
// elem (col,k) -> chunk c=k>>5, kblk=(k>>3)&3, dst elem = c*16384 + kblk*4096 + col*8 + (k&7)
struct Job { const void* base; int eoff; int n; int dstoff; int mode; };
struct Jobs { Job j[29]; };

__global__ __launch_bounds__(256) void k_convert(Jobs jobs, char* __restrict__ ws) {
  const Job jb = jobs.j[blockIdx.y];
  const int i0 = (blockIdx.x * 256 + threadIdx.x) * 8;
  if (i0 >= jb.n) return;
  u16* dst = (u16*)(ws + jb.dstoff);
  const float* src = (const float*)jb.base + jb.eoff;
  if (i0 + 8 <= jb.n) {
    const float4 a = *(const float4*)(src + i0);
    const float4 b = *(const float4*)(src + i0 + 4);
    u16 o[8] = {f2bf(a.x), f2bf(a.y), f2bf(a.z), f2bf(a.w),
                f2bf(b.x), f2bf(b.y), f2bf(b.z), f2bf(b.w)};
    int off = i0;
    if (jb.mode == 1) {
      const int col = i0 >> 9, k0 = i0 & 511;
      off = (k0 >> 5) * 16384 + ((k0 >> 3) & 3) * 4096 + col * 8;
    }
    *(uint4*)(dst + off) = *(uint4*)o;
  } else {
    for (int k = i0; k < jb.n; ++k) dst[k] = f2bf(src[k]);
  }
}

// ---- DMA staging: one 32KB chunk, 16 waves x 2KB (2 x 1KB gl_lds calls each)
__device__ __forceinline__ void stage32k(const char* gsrc, u16* lbuf, int wid, int lane) {
  const char* g = gsrc + wid * 2048 + lane * 16;
  u16* l = lbuf + wid * 1024;  // wave-uniform base; lane*16B added by HW
  gl_lds16(g, l);
  gl_lds16(g + 1024, l + 512);
}

// ---- streamed GEMM layer (16 waves, rows=16, cols=512), depth-3 pipeline.
// Chunks 0..2 of THIS layer must already be in flight/staged (bufs 0..2).
// Iter c: issue chunk c+3 (from this layer, or Wn's chunks 0..2 when c>=13);
// vmcnt(6) => chunk c's loads retired (6 = 3 chunks ahead x 2 loads/wave);
// barrier => ALL waves' chunk-c staging visible; ds_read+MFMA; barrier =>
// all reads of buf[c&3] done before its restage at iter c+1.
__device__ __forceinline__ void gemm_stream(const u16* Xlds, const char* Wg, const char* Wn,
                                            u16 (*__restrict__ WB)[16384], const u16* bias,
                                            int wid, int lane, f32x4 acc[2]) {
  const int rc = lane & 15, kb = lane >> 4;
  acc[0] = (f32x4){0.f, 0.f, 0.f, 0.f};
  acc[1] = acc[0];
#pragma unroll
  for (int c = 0; c < 16; ++c) {
    if (c < 13) stage32k(Wg + (c + 3) * CH, WB[(c + 3) & 3], wid, lane);
    else if (Wn) stage32k(Wn + (c - 13) * CH, WB[(c + 3) & 3], wid, lane);
    if (c < 13 || Wn) asm volatile("s_waitcnt vmcnt(6)" ::: "memory");
    else if (c == 13) asm volatile("s_waitcnt vmcnt(4)" ::: "memory");
    else if (c == 14) asm volatile("s_waitcnt vmcnt(2)" ::: "memory");
    else asm volatile("s_waitcnt vmcnt(0)" ::: "memory");
    __builtin_amdgcn_sched_barrier(0);
    __builtin_amdgcn_s_barrier();
    const u16* B = WB[c & 3];
    const bf16x8 a = *(const bf16x8*)&Xlds[rc * LSTR + c * 32 + kb * 8];
    const bf16x8 b0 = *(const bf16x8*)&B[kb * 4096 + (wid * 32 + rc) * 8];
    const bf16x8 b1 = *(const bf16x8*)&B[kb * 4096 + (wid * 32 + 16 + rc) * 8];
    acc[0] = MFMA(a, b0, acc[0]);
    acc[1] = MFMA(a, b1, acc[1]);
    __builtin_amdgcn_sched_barrier(0);
    __builtin_amdgcn_s_barrier();
  }
#pragma unroll
  for (int nt = 0; nt < 2; ++nt) {
    const float bv = bf2f(bias[wid * 32 + nt * 16 + rc]);
#pragma unroll
    for (int r = 0; r < 4; ++r) acc[nt][r] += bv;
  }
}

__device__ __forceinline__ void store_bf(u16* dst, int wid, int lane, const f32x4 acc[2]) {
  const int cr = lane & 15, rb = (lane >> 4) * 4;
#pragma unroll
  for (int nt = 0; nt < 2; ++nt) {
    const int col = wid * 32 + nt * 16 + cr;
#pragma unroll
    for (int r = 0; r < 4; ++r) dst[(rb + r) * LSTR + col] = f2bf(acc[nt][r]);
  }
}

// acc += src (bf16 LDS) over this wave's own columns (no cross-wave access)
__device__ __forceinline__ void add_lds_bf(const u16* src, int wid, int lane, f32x4 acc[2]) {
  const int cr = lane & 15, rb = (lane >> 4) * 4;
#pragma unroll
  for (int nt = 0; nt < 2; ++nt) {
    const int col = wid * 32 + nt * 16 + cr;
#pragma unroll
    for (int r = 0; r < 4; ++r) acc[nt][r] += bf2f(src[(rb + r) * LSTR + col]);
  }
}

__device__ __forceinline__ void add_glb_f32(const float* g, int wid, int lane, f32x4 acc[2]) {
  const int cr = lane & 15, rb = (lane >> 4) * 4;
#pragma unroll
  for (int nt = 0; nt < 2; ++nt) {
    const int col = wid * 32 + nt * 16 + cr;
#pragma unroll
    for (int r = 0; r < 4; ++r) acc[nt][r] += g[(size_t)(rb + r) * 512 + col];
  }
}

// LayerNorm row wid (wave-per-row), in-place safe (each elem read+written by same lane)
__device__ __forceinline__ void layer_norm_bf(const u16* X, u16* dst, const u16* g,
                                              const u16* b, int wid, int lane) {
  float s = 0.f, q = 0.f;
#pragma unroll
  for (int c = lane; c < 512; c += 64) {
    const float v = bf2f(X[wid * LSTR + c]);
    s += v; q += v * v;
  }
#pragma unroll
  for (int m = 1; m < 64; m <<= 1) {
    s += __shfl_xor(s, m, 64);
    q += __shfl_xor(q, m, 64);
  }
  const float mu = s * (1.f / 512.f);
  const float rs = rsqrtf(q * (1.f / 512.f) - mu * mu + 1e-5f);
#pragma unroll
  for (int c = lane; c < 512; c += 64) {
    const float v = (bf2f(X[wid * LSTR + c]) - mu) * rs * bf2f(g[c]) + bf2f(b[c]);
    dst[wid * LSTR + c] = f2bf(v);
  }
}

// ---- k_prot: pwr[p*4+j][col] for 8 pieces. 32 blocks = j(4) x colgrp(8), 256 thr.
__global__ __launch_bounds__(256) void k_prot(const char* __restrict__ ws,
                                              u16* __restrict__ pwr_ws) {
  __shared__ __align__(16) u16 A[16 * LSTR];
  const int tid = threadIdx.x, lane = tid & 63, wid = tid >> 6;
  const int j = blockIdx.x >> 3, g = blockIdx.x & 7;
  const u16* pemb = (const u16*)(ws + WS_PEMB);
  const u16* rot_w = (const u16*)(ws + WS_ROT);
  const u16* rot_b = (const u16*)(ws + WS_ROTB);
  for (int idx = tid; idx < 16 * 64; idx += 256) {
    const int r = idx >> 6, c = idx & 63;
    uint4 v;
    if (r < 8) v = ((const uint4*)pemb)[r * 64 + c];
    else { v.x = v.y = v.z = v.w = 0u; }
    *(uint4*)&A[r * LSTR + c * 8] = v;
  }
  __syncthreads();
  const int rc = lane & 15, kb = lane >> 4, rb = (lane >> 4) * 4;
  const int col = g * 64 + wid * 16 + rc;
  const bf16x8* ab = reinterpret_cast<const bf16x8*>(A) + rc * (LSTR / 8) + kb;
  const bf16x8* wb = reinterpret_cast<const bf16x8*>(rot_w) + ((size_t)(j * 512 + col)) * 64 + kb;
  f32x4 acc = (f32x4){0.f, 0.f, 0.f, 0.f};
#pragma unroll
  for (int ks = 0; ks < 16; ++ks) acc = MFMA(ab[ks * 4], wb[ks * 4], acc);
  const float bv = bf2f(rot_b[j * 512 + col]);
#pragma unroll
  for (int r = 0; r < 4; ++r) {
    const int p = rb + r;
    if (p < 8) pwr_ws[(size_t)(p * 4 + j) * 512 + col] = f2bf(acc[r] + bv);
  }
}

// ---- k_pkv: kk/vv[32][512] f32. 32 blocks = t(2) x colgrp(16), 256 thr.
__global__ __launch_bounds__(256) void k_pkv(const char* __restrict__ ws,
                                             const u16* __restrict__ pwr_ws,
                                             float* __restrict__ kk_ws,
                                             float* __restrict__ vv_ws) {
  __shared__ __align__(16) u16 A[32 * LSTR];
  const int tid = threadIdx.x, lane = tid & 63, wid = tid >> 6;
  const int t = blockIdx.x >> 4, g = blockIdx.x & 15;
  for (int idx = tid; idx < 32 * 64; idx += 256) {
    const int r = idx >> 6, c = idx & 63;
    *(uint4*)&A[r * LSTR + c * 8] = ((const uint4*)pwr_ws)[r * 64 + c];
  }
  __syncthreads();
  const u16* W = (const u16*)(ws + (t ? WS_VW : WS_KW));
  const u16* Bb = (const u16*)(ws + (t ? WS_VB : WS_KB));
  float* out = t ? vv_ws : kk_ws;
  const int rc = lane & 15, kb = lane >> 4, rb = (lane >> 4) * 4;
  const int rowt = wid >> 1;
  const int col = g * 32 + (wid & 1) * 16 + rc;
  const bf16x8* ab = reinterpret_cast<const bf16x8*>(A) + (rowt * 16 + rc) * (LSTR / 8) + kb;
  const bf16x8* wb = reinterpret_cast<const bf16x8*>(W) + (size_t)col * 64 + kb;
  f32x4 acc = (f32x4){0.f, 0.f, 0.f, 0.f};
#pragma unroll
  for (int ks = 0; ks < 16; ++ks) acc = MFMA(ab[ks * 4], wb[ks * 4], acc);
  const float bv = bf2f(Bb[col]);
#pragma unroll
  for (int r = 0; r < 4; ++r)
    out[(size_t)(rowt * 16 + rb + r) * 512 + col] = acc[r] + bv;
}

// ---- main fused chain: 32 blocks x 1024 threads (16 waves), 16 batch rows each.
// Single in-place activation buffer X; residuals in registers; continuous weight DMA.
__global__ __launch_bounds__(1024) void k_main(
    const float* __restrict__ state32, const float* __restrict__ mem32,
    const int* __restrict__ queue, const char* __restrict__ ws,
    const float* __restrict__ kk_ws, const float* __restrict__ vv_ws,
    float* __restrict__ out_pol, float* __restrict__ out_val) {
  __shared__ __align__(16) u16 X[16 * LSTR];
  __shared__ __align__(16) u16 WB[4][16384];  // 4 x 32KB weight chunks
  __shared__ int piece_s[16];
  __shared__ int qs_s;
  const int tid = threadIdx.x;
  const int lane = tid & 63, wid = tid >> 6;
  const int r0 = blockIdx.x * 16;

  const u16* a0v_b = (const u16*)(ws + WS_A0VB);
  const u16* a0o_b = (const u16*)(ws + WS_A0OB);
  const u16* q_b   = (const u16*)(ws + WS_QB);
  const u16* qkv_b = (const u16*)(ws + WS_QKVB);
  const u16* que_b = (const u16*)(ws + WS_QUEB);
  const u16* a1v_b = (const u16*)(ws + WS_A1VB);
  const u16* a1o_b = (const u16*)(ws + WS_A1OB);
  const u16* val_b = (const u16*)(ws + WS_VALB);
  const u16* pol_w = (const u16*)(ws + WS_POL);  const u16* pol_b = (const u16*)(ws + WS_POLB);
  const u16* an_g = (const u16*)(ws + WS_ANG);   const u16* an_b = (const u16*)(ws + WS_ANB);
  const u16* fn_g = (const u16*)(ws + WS_FNG);   const u16* fn_b = (const u16*)(ws + WS_FNB);

  // kick off the DMA stream immediately: L1 chunks 0..2
  stage32k(ws + WS_A0V, WB[0], wid, lane);
  stage32k(ws + WS_A0V + CH, WB[1], wid, lane);
  stage32k(ws + WS_A0V + 2 * CH, WB[2], wid, lane);

  // stage state rows (f32 -> bf16 LDS): 1024 threads x 8 elems = 16x512
  {
    const int r = tid >> 6, c8 = (tid & 63) * 8;
    const float* src = state32 + (size_t)(r0 + r) * 512 + c8;
    const float4 a = *(const float4*)src;
    const float4 b = *(const float4*)(src + 4);
    u16 o[8] = {f2bf(a.x), f2bf(a.y), f2bf(a.z), f2bf(a.w),
                f2bf(b.x), f2bf(b.y), f2bf(b.z), f2bf(b.w)};
    *(uint4*)&X[r * LSTR + c8] = *(uint4*)o;
  }
  if (tid == 0) {  // int64-vs-int32 probe (int64: odd u32 words all zero)
    int odd = 0;
    for (int i = 1; i < 128; i += 2) odd += (queue[i] != 0);
    qs_s = (odd == 0) ? 2 : 1;
  }
  LBAR();  // X + qs_s visible to all waves
  if (tid < 16) piece_s[tid] = queue[(size_t)(r0 + tid) * 5 * qs_s] & 7;
  // piece_s consumed after L1..L3's internal barriers -> ordering safe.

  f32x4 acc[2], res[2];
  // L1: v0 = state @ a0v^T                         X -> X
  gemm_stream(X, ws + WS_A0V, ws + WS_A0O, WB, a0v_b, wid, lane, acc);
  store_bf(X, wid, lane, acc);
  LBAR();
  // L2: s0 = v0 @ a0o^T                            X -> X ; residual to regs
  gemm_stream(X, ws + WS_A0O, ws + WS_QW, WB, a0o_b, wid, lane, acc);
  res[0] = acc[0]; res[1] = acc[1];
  store_bf(X, wid, lane, acc);
  LBAR();
  // L3: qv = s0 @ q_w^T                            X -> X
  gemm_stream(X, ws + WS_QW, ws + WS_QKV, WB, q_b, wid, lane, acc);
  store_bf(X, wid, lane, acc);
  LBAR();
  // 4-key attention, in place on X (thread (r,h) owns X[r][h*64..h*64+63])
  if (tid < 128) {
    const int r = tid >> 3, h = tid & 7;
    const int p = piece_s[r];
    const u16* qrow = &X[r * LSTR + h * 64];
    const float* kkp = kk_ws + (size_t)(p * 4) * 512 + h * 64;
    const float* vvp = vv_ws + (size_t)(p * 4) * 512 + h * 64;
    float lg[4];
#pragma unroll
    for (int jj = 0; jj < 4; ++jj) {
      float s = 0.f;
      const float* kj = kkp + jj * 512;
#pragma unroll
      for (int d = 0; d < 64; d += 4) {
        const float4 kv = *(const float4*)(kj + d);
        s += bf2f(qrow[d]) * kv.x + bf2f(qrow[d + 1]) * kv.y + bf2f(qrow[d + 2]) * kv.z +
             bf2f(qrow[d + 3]) * kv.w;
      }
      lg[jj] = s * 0.125f;
    }
    const float m = fmaxf(fmaxf(lg[0], lg[1]), fmaxf(lg[2], lg[3]));
    float e0 = __expf(lg[0] - m), e1 = __expf(lg[1] - m);
    float e2 = __expf(lg[2] - m), e3 = __expf(lg[3] - m);
    const float inv = 1.f / (e0 + e1 + e2 + e3);
    e0 *= inv; e1 *= inv; e2 *= inv; e3 *= inv;
    u16* orow = &X[r * LSTR + h * 64];
#pragma unroll
    for (int d = 0; d < 64; d += 4) {
      const float4 v0 = *(const float4*)(vvp + 0 * 512 + d);
      const float4 v1 = *(const float4*)(vvp + 1 * 512 + d);
      const float4 v2 = *(const float4*)(vvp + 2 * 512 + d);
      const float4 v3 = *(const float4*)(vvp + 3 * 512 + d);
      orow[d + 0] = f2bf(e0 * v0.x + e1 * v1.x + e2 * v2.x + e3 * v3.x);
      orow[d + 1] = f2bf(e0 * v0.y + e1 * v1.y + e2 * v2.y + e3 * v3.y);
      orow[d + 2] = f2bf(e0 * v0.z + e1 * v1.z + e2 * v2.z + e3 * v3.z);
      orow[d + 3] = f2bf(e0 * v0.w + e1 * v1.w + e2 * v2.w + e3 * v3.w);
    }
  }
  LBAR();
  // L4: x1 = s0(res) + attn @ qkv^T                X -> X ; LN1 in place
  gemm_stream(X, ws + WS_QKV, ws + WS_QUE, WB, qkv_b, wid, lane, acc);
  acc[0] += res[0]; acc[1] += res[1];
  store_bf(X, wid, lane, acc);
  LBAR();
  layer_norm_bf(X, X, an_g, an_b, wid, lane);
  LBAR();
  // L5: x2 = s1 + s1 @ que_w^T                     X -> X ; LN2 in place
  gemm_stream(X, ws + WS_QUE, ws + WS_A1V, WB, que_b, wid, lane, acc);
  add_lds_bf(X, wid, lane, acc);  // s1 still in X; wave-own cols only
  store_bf(X, wid, lane, acc);
  LBAR();
  layer_norm_bf(X, X, fn_g, fn_b, wid, lane);
  LBAR();
  // L6: v1 = s2 @ a1v^T                            X -> X
  gemm_stream(X, ws + WS_A1V, ws + WS_A1O, WB, a1v_b, wid, lane, acc);
  store_bf(X, wid, lane, acc);
  LBAR();
  // L7: xo = v1 @ a1o^T + memory                   X -> X
  gemm_stream(X, ws + WS_A1O, ws + WS_VAL, WB, a1o_b, wid, lane, acc);
  add_glb_f32(mem32 + (size_t)r0 * 512, wid, lane, acc);
  store_bf(X, wid, lane, acc);
  LBAR();
  // L8: val = xo @ val_w^T -> out (f32); X keeps xo
  gemm_stream(X, ws + WS_VAL, nullptr, WB, val_b, wid, lane, acc);
  {
    const int cr = lane & 15, rb = (lane >> 4) * 4;
#pragma unroll
    for (int nt = 0; nt < 2; ++nt) {
      const int col = wid * 32 + nt * 16 + cr;
#pragma unroll
      for (int r = 0; r < 4; ++r) out_val[(size_t)(r0 + rb + r) * 512 + col] = acc[nt][r];
    }
  }
  // L9: pol = xo @ pol_w^T (10 cols), wave 0 only
  if (wid == 0) {
    const int rc = lane & 15, kb = lane >> 4;
    const int wrow = rc < 10 ? rc : 0;
    const bf16x8* ab = reinterpret_cast<const bf16x8*>(X) + rc * (LSTR / 8) + kb;
    const bf16x8* wb = reinterpret_cast<const bf16x8*>(pol_w) + wrow * 64 + kb;
    f32x4 pa = (f32x4){0.f, 0.f, 0.f, 0.f};
#pragma unroll
    for (int ks = 0; ks < 16; ++ks) pa = MFMA(ab[ks * 4], wb[ks * 4], pa);
    if (rc < 10) {
      const float bv = bf2f(pol_b[rc]);
      const int rb = (lane >> 4) * 4;
#pragma unroll
      for (int r = 0; r < 4; ++r) out_pol[(size_t)(r0 + rb + r) * 10 + rc] = pa[r] + bv;
    }
  }
}

extern "C" void kernel_launch(void* const* d_in, const int* in_sizes, int n_in, void* d_out,
                              int out_size, void* d_ws, size_t ws_size, hipStream_t stream) {
  (void)in_sizes; (void)n_in; (void)out_size; (void)ws_size;
  char* ws = (char*)d_ws;

  Jobs jobs;
  int ji = 0;
  auto add = [&](int idx, int eoff, int n, int off, int mode) {
    jobs.j[ji].base = d_in[idx]; jobs.j[ji].eoff = eoff; jobs.j[ji].n = n;
    jobs.j[ji].dstoff = off; jobs.j[ji].mode = mode; ++ji;
  };
  add(38, 524288, 262144, WS_A0V, 1);   // a0_in_w rows [1024:1536] (v-slice)
  add(40, 0, 262144, WS_A0O, 1);
  add(12, 0, 262144, WS_QW, 1);
  add(18, 0, 262144, WS_QKV, 1);
  add(20, 0, 262144, WS_QUE, 1);
  add(42, 524288, 262144, WS_A1V, 1);   // a1_in_w rows [1024:1536]
  add(44, 0, 262144, WS_A1O, 1);
  add(48, 0, 262144, WS_VAL, 1);
  add(46, 0, 5120, WS_POL, 0);
  add(9, 0, 4096, WS_PEMB, 0);
  add(10, 0, 1048576, WS_ROT, 0);
  add(14, 0, 262144, WS_KW, 0);
  add(16, 0, 262144, WS_VW, 0);
  add(11, 0, 2048, WS_ROTB, 0);
  add(39, 1024, 512, WS_A0VB, 0);
  add(41, 0, 512, WS_A0OB, 0);
  add(13, 0, 512, WS_QB, 0);
  add(15, 0, 512, WS_KB, 0);
  add(17, 0, 512, WS_VB, 0);
  add(19, 0, 512, WS_QKVB, 0);
  add(21, 0, 512, WS_QUEB, 0);
  add(43, 1024, 512, WS_A1VB, 0);
  add(45, 0, 512, WS_A1OB, 0);
  add(49, 0, 512, WS_VALB, 0);
  add(22, 0, 512, WS_ANG, 0);
  add(23, 0, 512, WS_ANB, 0);
  add(24, 0, 512, WS_FNG, 0);
  add(25, 0, 512, WS_FNB, 0);
  add(47, 0, 10, WS_POLB, 0);

  k_convert<<<dim3(512, 29), dim3(256), 0, stream>>>(jobs, ws);
  k_prot<<<dim3(32), dim3(256), 0, stream>>>(ws, (u16*)(ws + WS_PWR));
  k_pkv<<<dim3(32), dim3(256), 0, stream>>>(ws, (const u16*)(ws + WS_PWR),
                                            (float*)(ws + WS_KK), (float*)(ws + WS_VV));

  float* out_pol = (float*)d_out;
  float* out_val = out_pol + 512 * 10;
  k_main<<<dim3(32), dim3(1024), 0, stream>>>(
      (const float*)d_in[3], (const float*)d_in[4], (const int*)d_in[1], (const char*)ws,
      (const float*)(ws + WS_KK), (const float*)(ws + WS_VV), out_pol, out_val);
}